// Round 8
// baseline (139.384 us; speedup 1.0000x reference)
//
#include <hip/hip_runtime.h>
#include <hip/hip_bf16.h>
#include <stdint.h>

#define BATCH 8192
#define IN    1024
#define OUTD  1024
#define PBASIS 8

typedef __attribute__((ext_vector_type(8))) short bf16x8;
typedef __attribute__((ext_vector_type(4))) float floatx4;

__device__ __forceinline__ unsigned short f2bf(float f) {
    union { float f; unsigned u; } v; v.f = f;
    unsigned u = v.u;
    u += 0x7fffu + ((u >> 16) & 1u);   // RNE; inputs finite randn
    return (unsigned short)(u >> 16);
}

// v_cvt_pk_bf16_f32: packs 2 f32 -> 2 bf16 (RNE), S0 -> low 16. Bit-identical
// to f2bf for finite inputs. No builtin on gfx950 [m240] -> inline asm.
__device__ __forceinline__ unsigned cvtpk(float lo, float hi) {
    unsigned r;
    asm("v_cvt_pk_bf16_f32 %0, %1, %2" : "=v"(r) : "v"(lo), "v"(hi));
    return r;
}

// prep: w_eff = bf16(sum_p coef * w), 2 elems/thread. 38 MB HBM (~6 us).
// x is no longer pre-converted: the GEMM consumes f32 x directly.
__global__ void prep_kernel(const float* __restrict__ coef,
                            const float* __restrict__ w,
                            unsigned short* __restrict__ weff) {
    int idx = blockIdx.x * 256 + threadIdx.x;    // element pair index
    size_t e0 = (size_t)idx * 2;
    const float4* c4 = (const float4*)(coef + e0 * PBASIS);
    float4 a = c4[0], bb = c4[1], c = c4[2], d = c4[3];
    float s0 = (a.x + a.y + a.z + a.w) + (bb.x + bb.y + bb.z + bb.w);
    float s1 = (c.x + c.y + c.z + c.w) + (d.x + d.y + d.z + d.w);
    float2 ww = ((const float2*)w)[idx];
    unsigned b0 = f2bf(s0 * ww.x);
    unsigned b1 = f2bf(s1 * ww.y);
    ((unsigned*)weff)[idx] = b0 | (b1 << 16);
}

__device__ __forceinline__ void gload_lds16(const void* g, void* l) {
    __builtin_amdgcn_global_load_lds(
        (const __attribute__((address_space(1))) unsigned int*)g,
        (__attribute__((address_space(3))) unsigned int*)l,
        16, 0, 0);
}

#define BARRIER()    asm volatile("s_barrier" ::: "memory")
#define WAIT_V10L0() asm volatile("s_waitcnt vmcnt(10) lgkmcnt(0)" ::: "memory")
#define WAIT_V0L0()  asm volatile("s_waitcnt vmcnt(0) lgkmcnt(0)" ::: "memory")

// C[m,n] = sum_k x[m,k]*B[n,k]; x=[8192,1024] f32, B=[1024,1024] bf16.
// BM=256 x BN=128, BK=64, 512 threads = 8 waves (4M x 2N), per-wave 64x64.
// Tri-buffered 3 x 48KB. R2's proven sync skeleton; ONLY change: A is
// consumed as f32 and converted in-kernel (kills the 48MB x-prep round
// trip). A path: depth-2 reg pipeline -- iter kt issues A(kt+2) f32 loads
// (8x dwordx4), cvt_pk+ds_writes A(kt+1) (4x b128) into stage (kt+1)%3,
// computes tile kt. B path unchanged: 2x global_load_lds per K-tile into
// stage (kt+2)%3. vmcnt invariant (order-robust): each iter issues exactly
// 10 VMEM ops (8 A-reg + 2 B-gload); closing vmcnt(10) keeps only this
// iter's ops in flight => all of iter kt-1 (incl. B(kt+1)) retired.
// lgkmcnt(0) covers A(kt+1) ds_writes + tile-kt ds_reads. Barriers and
// asm memory clobbers block cross-iteration motion. LDS layout (linear
// slot g, source column c^(row&7)) and K-accumulation order identical to
// R2 => bit-identical C, absmax 0.25.
__global__ __launch_bounds__(512, 2) void gemm_bt(
        const float* __restrict__ X,
        const unsigned short* __restrict__ B,
        float* __restrict__ C) {
    constexpr int K = IN, BK = 64, NT = K / BK;   // 16 K-steps
    constexpr int STG = 49152;                    // 48 KB (A 32K + B 16K)
    constexpr int ES = 132;                       // epilogue row stride (floats)
    __shared__ __align__(16) char smem[3 * STG];  // 144 KiB
    float* ebuf = (float*)smem;                   // epilogue reuse (132 KB)

    const int tid  = threadIdx.x;
    const int bm   = blockIdx.x, bn = blockIdx.y;
    const int lane = tid & 63;
    const int wave = tid >> 6;     // 0..7
    const int wm   = wave >> 1;    // 0..3 along M
    const int wn   = wave & 1;     // 0..1 along N
    const int t    = lane & 15;
    const int q    = lane >> 4;
    const int r8   = t & 7;        // XOR swizzle key

    // ---- A staging map: 4 chunks/thread/K-step ----
    // chunk g: row = g>>3 (0..255), c = g&7; LDS slot = g (linear);
    // global source column = c ^ (row&7) (involution) -> read f32 there.
    int g0 = tid,         ra0 = g0 >> 3, ca0 = (g0 & 7) ^ (ra0 & 7);
    int g1 = 512 + tid,   ra1 = g1 >> 3, ca1 = (g1 & 7) ^ (ra1 & 7);
    int g2 = 1024 + tid,  ra2 = g2 >> 3, ca2 = (g2 & 7) ^ (ra2 & 7);
    int g3 = 1536 + tid,  ra3 = g3 >> 3, ca3 = (g3 & 7) ^ (ra3 & 7);
    int h0 = tid,         rb0 = h0 >> 3, cb0 = (h0 & 7) ^ (rb0 & 7);
    int h1 = 512 + tid,   rb1 = h1 >> 3, cb1 = (h1 & 7) ^ (rb1 & 7);

    const float* gx0 = X + (size_t)(bm * 256 + ra0) * K + ca0 * 8;
    const float* gx1 = X + (size_t)(bm * 256 + ra1) * K + ca1 * 8;
    const float* gx2 = X + (size_t)(bm * 256 + ra2) * K + ca2 * 8;
    const float* gx3 = X + (size_t)(bm * 256 + ra3) * K + ca3 * 8;
    const unsigned short* gB0 = B + (size_t)(bn * 128 + rb0) * K + cb0 * 8;
    const unsigned short* gB1 = B + (size_t)(bn * 128 + rb1) * K + cb1 * 8;

    const int dA0 = g0 * 16, dA1 = g1 * 16, dA2 = g2 * 16, dA3 = g3 * 16;
    const int dB0 = 32768 + h0 * 16, dB1 = 32768 + h1 * 16;

    // ---- fragment byte offsets within a stage (A at 0, B at 32768) ----
    const int aO0 = ((wm * 64 + t) * 64 + ((0 + q) ^ r8) * 8) * 2;
    const int aO1 = ((wm * 64 + t) * 64 + ((4 + q) ^ r8) * 8) * 2;
    const int bO0 = 32768 + ((wn * 64 + t) * 64 + ((0 + q) ^ r8) * 8) * 2;
    const int bO1 = 32768 + ((wn * 64 + t) * 64 + ((4 + q) ^ r8) * 8) * 2;

    floatx4 acc[4][4];
#pragma unroll
    for (int i = 0; i < 4; ++i)
#pragma unroll
        for (int j = 0; j < 4; ++j)
            acc[i][j] = (floatx4){0.f, 0.f, 0.f, 0.f};

#define ISSUE_A(d0,d1,d2,d3,d4,d5,d6,d7, kf)                        \
    {                                                               \
        d0 = *(const float4*)(gx0 + (kf));                          \
        d1 = *(const float4*)(gx0 + (kf) + 4);                      \
        d2 = *(const float4*)(gx1 + (kf));                          \
        d3 = *(const float4*)(gx1 + (kf) + 4);                      \
        d4 = *(const float4*)(gx2 + (kf));                          \
        d5 = *(const float4*)(gx2 + (kf) + 4);                      \
        d6 = *(const float4*)(gx3 + (kf));                          \
        d7 = *(const float4*)(gx3 + (kf) + 4);                      \
    }
#define STAGE_B(sp, ko)                                             \
    {                                                               \
        gload_lds16(gB0 + (ko), (sp) + dB0);                        \
        gload_lds16(gB1 + (ko), (sp) + dB1);                        \
    }
#define CVT_WRITE(sw, s0,s1,s2,s3,s4,s5,s6,s7)                      \
    {                                                               \
        uint4 v;                                                    \
        v.x = cvtpk(s0.x, s0.y); v.y = cvtpk(s0.z, s0.w);           \
        v.z = cvtpk(s1.x, s1.y); v.w = cvtpk(s1.z, s1.w);           \
        *(uint4*)((sw) + dA0) = v;                                  \
        v.x = cvtpk(s2.x, s2.y); v.y = cvtpk(s2.z, s2.w);           \
        v.z = cvtpk(s3.x, s3.y); v.w = cvtpk(s3.z, s3.w);           \
        *(uint4*)((sw) + dA1) = v;                                  \
        v.x = cvtpk(s4.x, s4.y); v.y = cvtpk(s4.z, s4.w);           \
        v.z = cvtpk(s5.x, s5.y); v.w = cvtpk(s5.z, s5.w);           \
        *(uint4*)((sw) + dA2) = v;                                  \
        v.x = cvtpk(s6.x, s6.y); v.y = cvtpk(s6.z, s6.w);           \
        v.z = cvtpk(s7.x, s7.y); v.w = cvtpk(s7.z, s7.w);           \
        *(uint4*)((sw) + dA3) = v;                                  \
    }
#define PHASE(sb, aO, bO)                                           \
    {                                                               \
        const char* ab = (const char*)(sb) + (aO);                  \
        const char* bb = (const char*)(sb) + (bO);                  \
        bf16x8 af0 = *(const bf16x8*)(ab + 0 * 2048);               \
        bf16x8 af1 = *(const bf16x8*)(ab + 1 * 2048);               \
        bf16x8 af2 = *(const bf16x8*)(ab + 2 * 2048);               \
        bf16x8 af3 = *(const bf16x8*)(ab + 3 * 2048);               \
        bf16x8 bf0 = *(const bf16x8*)(bb + 0 * 2048);               \
        bf16x8 bf1 = *(const bf16x8*)(bb + 1 * 2048);               \
        bf16x8 bf2 = *(const bf16x8*)(bb + 2 * 2048);               \
        bf16x8 bf3 = *(const bf16x8*)(bb + 3 * 2048);               \
        bf16x8 afv[4] = {af0, af1, af2, af3};                       \
        bf16x8 bfv[4] = {bf0, bf1, bf2, bf3};                       \
        __builtin_amdgcn_s_setprio(1);                              \
        _Pragma("unroll")                                           \
        for (int i = 0; i < 4; ++i)                                 \
            _Pragma("unroll")                                       \
            for (int j = 0; j < 4; ++j)                             \
                acc[i][j] = __builtin_amdgcn_mfma_f32_16x16x32_bf16(\
                    afv[i], bfv[j], acc[i][j], 0, 0, 0);            \
        __builtin_amdgcn_s_setprio(0);                              \
    }

    float4 pa0, pa1, pa2, pa3, pa4, pa5, pa6, pa7;   // A(kt+1) f32
    float4 na0, na1, na2, na3, na4, na5, na6, na7;   // A(kt+2) f32

    // ---- prologue ----
    // A(0)->na, B(0)->s0, A(1)->pa, B(1)->s1; cvt+write A(0)->s0;
    // vmcnt(10): B(0) retired, A(1)+B(1)=10 in flight.
    ISSUE_A(na0,na1,na2,na3,na4,na5,na6,na7, 0);
    STAGE_B(smem, 0);
    ISSUE_A(pa0,pa1,pa2,pa3,pa4,pa5,pa6,pa7, 64);
    STAGE_B(smem + STG, BK);
    CVT_WRITE(smem, na0,na1,na2,na3,na4,na5,na6,na7);
    WAIT_V10L0();
    BARRIER();

    // ---- main loop: 2x-unrolled ping-pong, kt = 0..13 ----
    int cur = 0;
    for (int it = 0; it < 7; ++it) {
        const int kt0 = 2 * it, kt1 = kt0 + 1;
        {   // even: pa = A(kt0+1); load na = A(kt0+2)
            char* sb = smem + cur * STG;
            int w1 = cur + 1; if (w1 >= 3) w1 -= 3;
            int p2 = cur + 2; if (p2 >= 3) p2 -= 3;
            ISSUE_A(na0,na1,na2,na3,na4,na5,na6,na7, (kt0 + 2) * 64);
            STAGE_B(smem + p2 * STG, (kt0 + 2) * BK);
            CVT_WRITE(smem + w1 * STG, pa0,pa1,pa2,pa3,pa4,pa5,pa6,pa7);
            PHASE(sb, aO0, bO0);
            PHASE(sb, aO1, bO1);
            WAIT_V10L0();
            BARRIER();
            cur = w1;
        }
        {   // odd: na = A(kt1+1); load pa = A(kt1+2)
            char* sb = smem + cur * STG;
            int w1 = cur + 1; if (w1 >= 3) w1 -= 3;
            int p2 = cur + 2; if (p2 >= 3) p2 -= 3;
            ISSUE_A(pa0,pa1,pa2,pa3,pa4,pa5,pa6,pa7, (kt1 + 2) * 64);
            STAGE_B(smem + p2 * STG, (kt1 + 2) * BK);
            CVT_WRITE(smem + w1 * STG, na0,na1,na2,na3,na4,na5,na6,na7);
            PHASE(sb, aO0, bO0);
            PHASE(sb, aO1, bO1);
            WAIT_V10L0();
            BARRIER();
            cur = w1;
        }
    }
    {   // kt = 14: pa = A(15); no new issues; write A(15); drain
        char* sb = smem + cur * STG;
        int w1 = cur + 1; if (w1 >= 3) w1 -= 3;
        CVT_WRITE(smem + w1 * STG, pa0,pa1,pa2,pa3,pa4,pa5,pa6,pa7);
        PHASE(sb, aO0, bO0);
        PHASE(sb, aO1, bO1);
        WAIT_V0L0();
        BARRIER();
        cur = w1;
    }
    {   // kt = 15
        char* sb = smem + cur * STG;
        PHASE(sb, aO0, bO0);
        PHASE(sb, aO1, bO1);
    }
#undef PHASE
#undef CVT_WRITE
#undef STAGE_B
#undef ISSUE_A

    __syncthreads();   // full drain before LDS reuse as ebuf

    // ---- epilogue: dump 256x128 f32 via LDS (ES=132 pad), float4 out ----
    // D layout: col = t, row = q*4 + r  [m89/m91 verified]
#pragma unroll
    for (int tm = 0; tm < 4; ++tm)
#pragma unroll
        for (int tn = 0; tn < 4; ++tn)
#pragma unroll
            for (int r = 0; r < 4; ++r)
                ebuf[(wm * 64 + tm * 16 + q * 4 + r) * ES
                     + wn * 64 + tn * 16 + t] = acc[tm][tn][r];
    __syncthreads();
#pragma unroll
    for (int ps = 0; ps < 16; ++ps) {
        int row  = ps * 16 + (tid >> 5);
        int col4 = tid & 31;
        float4 v = *(const float4*)(ebuf + row * ES + col4 * 4);
        *(float4*)(C + (size_t)(bm * 256 + row) * OUTD + bn * 128 + col4 * 4) = v;
    }
}

extern "C" void kernel_launch(void* const* d_in, const int* in_sizes, int n_in,
                              void* d_out, int out_size, void* d_ws, size_t ws_size,
                              hipStream_t stream) {
    const float* x    = (const float*)d_in[0];
    const float* coef = (const float*)d_in[1];
    const float* w    = (const float*)d_in[2];
    float* out = (float*)d_out;

    unsigned short* weff = (unsigned short*)d_ws;   // 2 MB

    prep_kernel<<<2048, 256, 0, stream>>>(coef, w, weff);
    gemm_bt<<<dim3(BATCH / 256, OUTD / 128), 512, 0, stream>>>(x, weff, out);
}

// Round 9
// 138.678 us; speedup vs baseline: 1.0051x; 1.0051x over previous
//
#include <hip/hip_runtime.h>
#include <hip/hip_bf16.h>
#include <stdint.h>

#define BATCH 8192
#define IN    1024
#define OUTD  1024
#define PBASIS 8

typedef __attribute__((ext_vector_type(8))) short bf16x8;
typedef __attribute__((ext_vector_type(4))) float floatx4;

__device__ __forceinline__ unsigned short f2bf(float f) {
    union { float f; unsigned u; } v; v.f = f;
    unsigned u = v.u;
    u += 0x7fffu + ((u >> 16) & 1u);   // RNE; inputs finite randn
    return (unsigned short)(u >> 16);
}

// v_cvt_pk_bf16_f32: packs 2 f32 -> 2 bf16 (RNE), S0 -> low 16. Bit-identical
// to f2bf for finite inputs. No builtin on gfx950 [m240] -> inline asm.
__device__ __forceinline__ unsigned cvtpk(float lo, float hi) {
    unsigned r;
    asm("v_cvt_pk_bf16_f32 %0, %1, %2" : "=v"(r) : "v"(lo), "v"(hi));
    return r;
}

// prep: w_eff = bf16(sum_p coef * w), 2 elems/thread. 38 MB HBM (~6 us).
// x is no longer pre-converted: the GEMM consumes f32 x directly.
__global__ void prep_kernel(const float* __restrict__ coef,
                            const float* __restrict__ w,
                            unsigned short* __restrict__ weff) {
    int idx = blockIdx.x * 256 + threadIdx.x;    // element pair index
    size_t e0 = (size_t)idx * 2;
    const float4* c4 = (const float4*)(coef + e0 * PBASIS);
    float4 a = c4[0], bb = c4[1], c = c4[2], d = c4[3];
    float s0 = (a.x + a.y + a.z + a.w) + (bb.x + bb.y + bb.z + bb.w);
    float s1 = (c.x + c.y + c.z + c.w) + (d.x + d.y + d.z + d.w);
    float2 ww = ((const float2*)w)[idx];
    unsigned b0 = f2bf(s0 * ww.x);
    unsigned b1 = f2bf(s1 * ww.y);
    ((unsigned*)weff)[idx] = b0 | (b1 << 16);
}

__device__ __forceinline__ void gload_lds16(const void* g, void* l) {
    __builtin_amdgcn_global_load_lds(
        (const __attribute__((address_space(1))) unsigned int*)g,
        (__attribute__((address_space(3))) unsigned int*)l,
        16, 0, 0);
}

#define BARRIER()    asm volatile("s_barrier" ::: "memory")
#define WAIT_V10L0() asm volatile("s_waitcnt vmcnt(10) lgkmcnt(0)" ::: "memory")
#define WAIT_V0L0()  asm volatile("s_waitcnt vmcnt(0) lgkmcnt(0)" ::: "memory")

// C[m,n] = sum_k x[m,k]*B[n,k]; x=[8192,1024] f32, B=[1024,1024] bf16.
// BM=256 x BN=128, BK=64, 512 threads = 8 waves (4M x 2N), per-wave 64x64.
// Tri-buffered 3 x 48KB = 144 KiB (LDS-capped at 1 block/CU regardless of
// launch_bounds). R2's proven sync skeleton; A consumed as f32, converted
// in-kernel (kills the 48MB x-prep round trip).
//
// R9 fix vs R8 (passed but 49us): __launch_bounds__(512, 2) capped the
// allocator at 128 VGPR while the depth-2 A-reg pipeline needs ~170
// (16 live float4 staging + 64 acc + frags) -> VGPR_Count=88 with scratch
// spill, MfmaUtil 12.6%. The cap bought nothing: LDS already limits to
// 1 block/CU. Now (512, 1): 256 VGPR budget, no spill, same occupancy.
//
// A path: depth-2 reg pipeline -- iter kt issues A(kt+2) f32 loads
// (8x dwordx4), cvt_pk+ds_writes A(kt+1) (4x b128) into stage (kt+1)%3,
// computes tile kt. B path: 2x global_load_lds per K-tile into stage
// (kt+2)%3. vmcnt invariant (order-robust): each iter issues exactly 10
// VMEM ops (8 A-reg + 2 B-gload); closing vmcnt(10) keeps only this
// iter's ops in flight => all of iter kt-1 (incl. B(kt+1)) retired.
// Compiler tracks A-reg load results for CVT_WRITE's cross-barrier use.
// LDS layout (linear slot g, source column c^(row&7)) and K-accumulation
// order identical to R2 => bit-identical C, absmax 0.25 (R8-verified).
__global__ __launch_bounds__(512, 1) void gemm_bt(
        const float* __restrict__ X,
        const unsigned short* __restrict__ B,
        float* __restrict__ C) {
    constexpr int K = IN, BK = 64, NT = K / BK;   // 16 K-steps
    constexpr int STG = 49152;                    // 48 KB (A 32K + B 16K)
    constexpr int ES = 132;                       // epilogue row stride (floats)
    __shared__ __align__(16) char smem[3 * STG];  // 144 KiB
    float* ebuf = (float*)smem;                   // epilogue reuse (132 KB)

    const int tid  = threadIdx.x;
    const int bm   = blockIdx.x, bn = blockIdx.y;
    const int lane = tid & 63;
    const int wave = tid >> 6;     // 0..7
    const int wm   = wave >> 1;    // 0..3 along M
    const int wn   = wave & 1;     // 0..1 along N
    const int t    = lane & 15;
    const int q    = lane >> 4;
    const int r8   = t & 7;        // XOR swizzle key

    // ---- A staging map: 4 chunks/thread/K-step ----
    // chunk g: row = g>>3 (0..255), c = g&7; LDS slot = g (linear);
    // global source column = c ^ (row&7) (involution) -> read f32 there.
    int g0 = tid,         ra0 = g0 >> 3, ca0 = (g0 & 7) ^ (ra0 & 7);
    int g1 = 512 + tid,   ra1 = g1 >> 3, ca1 = (g1 & 7) ^ (ra1 & 7);
    int g2 = 1024 + tid,  ra2 = g2 >> 3, ca2 = (g2 & 7) ^ (ra2 & 7);
    int g3 = 1536 + tid,  ra3 = g3 >> 3, ca3 = (g3 & 7) ^ (ra3 & 7);
    int h0 = tid,         rb0 = h0 >> 3, cb0 = (h0 & 7) ^ (rb0 & 7);
    int h1 = 512 + tid,   rb1 = h1 >> 3, cb1 = (h1 & 7) ^ (rb1 & 7);

    const float* gx0 = X + (size_t)(bm * 256 + ra0) * K + ca0 * 8;
    const float* gx1 = X + (size_t)(bm * 256 + ra1) * K + ca1 * 8;
    const float* gx2 = X + (size_t)(bm * 256 + ra2) * K + ca2 * 8;
    const float* gx3 = X + (size_t)(bm * 256 + ra3) * K + ca3 * 8;
    const unsigned short* gB0 = B + (size_t)(bn * 128 + rb0) * K + cb0 * 8;
    const unsigned short* gB1 = B + (size_t)(bn * 128 + rb1) * K + cb1 * 8;

    const int dA0 = g0 * 16, dA1 = g1 * 16, dA2 = g2 * 16, dA3 = g3 * 16;
    const int dB0 = 32768 + h0 * 16, dB1 = 32768 + h1 * 16;

    // ---- fragment byte offsets within a stage (A at 0, B at 32768) ----
    const int aO0 = ((wm * 64 + t) * 64 + ((0 + q) ^ r8) * 8) * 2;
    const int aO1 = ((wm * 64 + t) * 64 + ((4 + q) ^ r8) * 8) * 2;
    const int bO0 = 32768 + ((wn * 64 + t) * 64 + ((0 + q) ^ r8) * 8) * 2;
    const int bO1 = 32768 + ((wn * 64 + t) * 64 + ((4 + q) ^ r8) * 8) * 2;

    floatx4 acc[4][4];
#pragma unroll
    for (int i = 0; i < 4; ++i)
#pragma unroll
        for (int j = 0; j < 4; ++j)
            acc[i][j] = (floatx4){0.f, 0.f, 0.f, 0.f};

#define ISSUE_A(d0,d1,d2,d3,d4,d5,d6,d7, kf)                        \
    {                                                               \
        d0 = *(const float4*)(gx0 + (kf));                          \
        d1 = *(const float4*)(gx0 + (kf) + 4);                      \
        d2 = *(const float4*)(gx1 + (kf));                          \
        d3 = *(const float4*)(gx1 + (kf) + 4);                      \
        d4 = *(const float4*)(gx2 + (kf));                          \
        d5 = *(const float4*)(gx2 + (kf) + 4);                      \
        d6 = *(const float4*)(gx3 + (kf));                          \
        d7 = *(const float4*)(gx3 + (kf) + 4);                      \
    }
#define STAGE_B(sp, ko)                                             \
    {                                                               \
        gload_lds16(gB0 + (ko), (sp) + dB0);                        \
        gload_lds16(gB1 + (ko), (sp) + dB1);                        \
    }
#define CVT_WRITE(sw, s0,s1,s2,s3,s4,s5,s6,s7)                      \
    {                                                               \
        uint4 v;                                                    \
        v.x = cvtpk(s0.x, s0.y); v.y = cvtpk(s0.z, s0.w);           \
        v.z = cvtpk(s1.x, s1.y); v.w = cvtpk(s1.z, s1.w);           \
        *(uint4*)((sw) + dA0) = v;                                  \
        v.x = cvtpk(s2.x, s2.y); v.y = cvtpk(s2.z, s2.w);           \
        v.z = cvtpk(s3.x, s3.y); v.w = cvtpk(s3.z, s3.w);           \
        *(uint4*)((sw) + dA1) = v;                                  \
        v.x = cvtpk(s4.x, s4.y); v.y = cvtpk(s4.z, s4.w);           \
        v.z = cvtpk(s5.x, s5.y); v.w = cvtpk(s5.z, s5.w);           \
        *(uint4*)((sw) + dA2) = v;                                  \
        v.x = cvtpk(s6.x, s6.y); v.y = cvtpk(s6.z, s6.w);           \
        v.z = cvtpk(s7.x, s7.y); v.w = cvtpk(s7.z, s7.w);           \
        *(uint4*)((sw) + dA3) = v;                                  \
    }
#define PHASE(sb, aO, bO)                                           \
    {                                                               \
        const char* ab = (const char*)(sb) + (aO);                  \
        const char* bb = (const char*)(sb) + (bO);                  \
        bf16x8 af0 = *(const bf16x8*)(ab + 0 * 2048);               \
        bf16x8 af1 = *(const bf16x8*)(ab + 1 * 2048);               \
        bf16x8 af2 = *(const bf16x8*)(ab + 2 * 2048);               \
        bf16x8 af3 = *(const bf16x8*)(ab + 3 * 2048);               \
        bf16x8 bf0 = *(const bf16x8*)(bb + 0 * 2048);               \
        bf16x8 bf1 = *(const bf16x8*)(bb + 1 * 2048);               \
        bf16x8 bf2 = *(const bf16x8*)(bb + 2 * 2048);               \
        bf16x8 bf3 = *(const bf16x8*)(bb + 3 * 2048);               \
        bf16x8 afv[4] = {af0, af1, af2, af3};                       \
        bf16x8 bfv[4] = {bf0, bf1, bf2, bf3};                       \
        __builtin_amdgcn_s_setprio(1);                              \
        _Pragma("unroll")                                           \
        for (int i = 0; i < 4; ++i)                                 \
            _Pragma("unroll")                                       \
            for (int j = 0; j < 4; ++j)                             \
                acc[i][j] = __builtin_amdgcn_mfma_f32_16x16x32_bf16(\
                    afv[i], bfv[j], acc[i][j], 0, 0, 0);            \
        __builtin_amdgcn_s_setprio(0);                              \
    }

    float4 pa0, pa1, pa2, pa3, pa4, pa5, pa6, pa7;   // A(kt+1) f32
    float4 na0, na1, na2, na3, na4, na5, na6, na7;   // A(kt+2) f32

    // ---- prologue ----
    // A(0)->na, B(0)->s0, A(1)->pa, B(1)->s1; cvt+write A(0)->s0;
    // vmcnt(10): B(0) retired, A(1)+B(1)=10 in flight.
    ISSUE_A(na0,na1,na2,na3,na4,na5,na6,na7, 0);
    STAGE_B(smem, 0);
    ISSUE_A(pa0,pa1,pa2,pa3,pa4,pa5,pa6,pa7, 64);
    STAGE_B(smem + STG, BK);
    CVT_WRITE(smem, na0,na1,na2,na3,na4,na5,na6,na7);
    WAIT_V10L0();
    BARRIER();

    // ---- main loop: 2x-unrolled ping-pong, kt = 0..13 ----
    int cur = 0;
    for (int it = 0; it < 7; ++it) {
        const int kt0 = 2 * it, kt1 = kt0 + 1;
        {   // even: pa = A(kt0+1); load na = A(kt0+2)
            char* sb = smem + cur * STG;
            int w1 = cur + 1; if (w1 >= 3) w1 -= 3;
            int p2 = cur + 2; if (p2 >= 3) p2 -= 3;
            ISSUE_A(na0,na1,na2,na3,na4,na5,na6,na7, (kt0 + 2) * 64);
            STAGE_B(smem + p2 * STG, (kt0 + 2) * BK);
            CVT_WRITE(smem + w1 * STG, pa0,pa1,pa2,pa3,pa4,pa5,pa6,pa7);
            PHASE(sb, aO0, bO0);
            PHASE(sb, aO1, bO1);
            WAIT_V10L0();
            BARRIER();
            cur = w1;
        }
        {   // odd: na = A(kt1+1); load pa = A(kt1+2)
            char* sb = smem + cur * STG;
            int w1 = cur + 1; if (w1 >= 3) w1 -= 3;
            int p2 = cur + 2; if (p2 >= 3) p2 -= 3;
            ISSUE_A(pa0,pa1,pa2,pa3,pa4,pa5,pa6,pa7, (kt1 + 2) * 64);
            STAGE_B(smem + p2 * STG, (kt1 + 2) * BK);
            CVT_WRITE(smem + w1 * STG, na0,na1,na2,na3,na4,na5,na6,na7);
            PHASE(sb, aO0, bO0);
            PHASE(sb, aO1, bO1);
            WAIT_V10L0();
            BARRIER();
            cur = w1;
        }
    }
    {   // kt = 14: pa = A(15); no new issues; write A(15); drain
        char* sb = smem + cur * STG;
        int w1 = cur + 1; if (w1 >= 3) w1 -= 3;
        CVT_WRITE(smem + w1 * STG, pa0,pa1,pa2,pa3,pa4,pa5,pa6,pa7);
        PHASE(sb, aO0, bO0);
        PHASE(sb, aO1, bO1);
        WAIT_V0L0();
        BARRIER();
        cur = w1;
    }
    {   // kt = 15
        char* sb = smem + cur * STG;
        PHASE(sb, aO0, bO0);
        PHASE(sb, aO1, bO1);
    }
#undef PHASE
#undef CVT_WRITE
#undef STAGE_B
#undef ISSUE_A

    __syncthreads();   // full drain before LDS reuse as ebuf

    // ---- epilogue: dump 256x128 f32 via LDS (ES=132 pad), float4 out ----
    // D layout: col = t, row = q*4 + r  [m89/m91 verified]
#pragma unroll
    for (int tm = 0; tm < 4; ++tm)
#pragma unroll
        for (int tn = 0; tn < 4; ++tn)
#pragma unroll
            for (int r = 0; r < 4; ++r)
                ebuf[(wm * 64 + tm * 16 + q * 4 + r) * ES
                     + wn * 64 + tn * 16 + t] = acc[tm][tn][r];
    __syncthreads();
#pragma unroll
    for (int ps = 0; ps < 16; ++ps) {
        int row  = ps * 16 + (tid >> 5);
        int col4 = tid & 31;
        float4 v = *(const float4*)(ebuf + row * ES + col4 * 4);
        *(float4*)(C + (size_t)(bm * 256 + row) * OUTD + bn * 128 + col4 * 4) = v;
    }
}

extern "C" void kernel_launch(void* const* d_in, const int* in_sizes, int n_in,
                              void* d_out, int out_size, void* d_ws, size_t ws_size,
                              hipStream_t stream) {
    const float* x    = (const float*)d_in[0];
    const float* coef = (const float*)d_in[1];
    const float* w    = (const float*)d_in[2];
    float* out = (float*)d_out;

    unsigned short* weff = (unsigned short*)d_ws;   // 2 MB

    prep_kernel<<<2048, 256, 0, stream>>>(coef, w, weff);
    gemm_bt<<<dim3(BATCH / 256, OUTD / 128), 512, 0, stream>>>(x, weff, out);
}

// Round 10
// 131.908 us; speedup vs baseline: 1.0567x; 1.0513x over previous
//
#include <hip/hip_runtime.h>
#include <hip/hip_bf16.h>
#include <stdint.h>

#define BATCH 8192
#define IN    1024
#define OUTD  1024
#define PBASIS 8

typedef __attribute__((ext_vector_type(8))) short bf16x8;
typedef __attribute__((ext_vector_type(4))) float floatx4;

__device__ __forceinline__ unsigned short f2bf(float f) {
    union { float f; unsigned u; } v; v.f = f;
    unsigned u = v.u;
    u += 0x7fffu + ((u >> 16) & 1u);   // RNE; inputs finite randn
    return (unsigned short)(u >> 16);
}

// v_cvt_pk_bf16_f32: packs 2 f32 -> 2 bf16 (RNE), S0 -> low 16. Bit-identical
// to f2bf for finite inputs. No builtin on gfx950 [m240] -> inline asm.
__device__ __forceinline__ unsigned cvtpk(float lo, float hi) {
    unsigned r;
    asm("v_cvt_pk_bf16_f32 %0, %1, %2" : "=v"(r) : "v"(lo), "v"(hi));
    return r;
}

// prep: w_eff = bf16(sum_p coef * w), 2 elems/thread. 38 MB HBM (~6 us).
__global__ void prep_kernel(const float* __restrict__ coef,
                            const float* __restrict__ w,
                            unsigned short* __restrict__ weff) {
    int idx = blockIdx.x * 256 + threadIdx.x;    // element pair index
    size_t e0 = (size_t)idx * 2;
    const float4* c4 = (const float4*)(coef + e0 * PBASIS);
    float4 a = c4[0], bb = c4[1], c = c4[2], d = c4[3];
    float s0 = (a.x + a.y + a.z + a.w) + (bb.x + bb.y + bb.z + bb.w);
    float s1 = (c.x + c.y + c.z + c.w) + (d.x + d.y + d.z + d.w);
    float2 ww = ((const float2*)w)[idx];
    unsigned b0 = f2bf(s0 * ww.x);
    unsigned b1 = f2bf(s1 * ww.y);
    ((unsigned*)weff)[idx] = b0 | (b1 << 16);
}

__device__ __forceinline__ void gload_lds16(const void* g, void* l) {
    __builtin_amdgcn_global_load_lds(
        (const __attribute__((address_space(1))) unsigned int*)g,
        (__attribute__((address_space(3))) unsigned int*)l,
        16, 0, 0);
}

#define BARRIER()    asm volatile("s_barrier" ::: "memory")
#define WAIT_V10L0() asm volatile("s_waitcnt vmcnt(10) lgkmcnt(0)" ::: "memory")
#define WAIT_V0L0()  asm volatile("s_waitcnt vmcnt(0) lgkmcnt(0)" ::: "memory")

// C[m,n] = sum_k x[m,k]*B[n,k]; x=[8192,1024] f32, B=[1024,1024] bf16.
// BM=256 x BN=128, BK=64, 512 threads = 8 waves (4M x 2N), per-wave 64x64.
// Tri-buffered 3 x 48KB; x consumed as f32, converted in-kernel.
//
// R10 fix vs R8/R9 (49us, MfmaUtil 12%): those placed CVT_WRITE (which
// needs the vmcnt-wait for A(kt+1)'s global loads) BEFORE the PHASEs.
// LDS ops execute in wave program order, so the compiler's vmcnt wait
// ahead of the ds_writes also blocked PHASE's ds_reads + MFMAs -- tile
// kt's ready compute stalled on tile kt+1's load returns (synchronous
// prefetch). Evidence: R6/R8/R9 (consumer-before-compute) all 49us;
// R0/R1/R2/R5/R7 (fire-and-forget staging) all 26-30us. Fix = T14
// issue-early/write-late: per step
//   { ISSUE_A(kt+2); STAGE_B(kt+2); PHASE(kt) x2; CVT_WRITE(A kt+1);
//     vmcnt(10) lgkmcnt(0); s_barrier }
// The pa-load wait now lands after ~600cyc of MFMAs (covered). Hazards:
// CVT_WRITE writes stage (cur+1), last read in iter kt-2 (2 barriers
// ago) -- safe. B gload_lds writes stage (cur+2), last read iter kt-1,
// whose reads retired before its closing barrier -- safe. vmcnt: exactly
// 10 VMEM issued/step; at the closing wait the 10 outstanding are this
// step's own (pa's 8 were forced complete by the cvts) => A/B(kt+1)
// landed, A/B(kt+2) in flight. K-accumulation order identical to R2 =>
// bit-identical C, absmax 0.25 (R8/R9-verified).
__global__ __launch_bounds__(512, 1) void gemm_bt(
        const float* __restrict__ X,
        const unsigned short* __restrict__ B,
        float* __restrict__ C) {
    constexpr int K = IN, BK = 64, NT = K / BK;   // 16 K-steps
    constexpr int STG = 49152;                    // 48 KB (A 32K + B 16K)
    constexpr int ES = 132;                       // epilogue row stride (floats)
    __shared__ __align__(16) char smem[3 * STG];  // 144 KiB
    float* ebuf = (float*)smem;                   // epilogue reuse (132 KB)

    const int tid  = threadIdx.x;
    const int bm   = blockIdx.x, bn = blockIdx.y;
    const int lane = tid & 63;
    const int wave = tid >> 6;     // 0..7
    const int wm   = wave >> 1;    // 0..3 along M
    const int wn   = wave & 1;     // 0..1 along N
    const int t    = lane & 15;
    const int q    = lane >> 4;
    const int r8   = t & 7;        // XOR swizzle key

    // ---- A staging map: 4 chunks/thread/K-step ----
    // chunk g: row = g>>3 (0..255), c = g&7; LDS slot = g (linear);
    // global source column = c ^ (row&7) (involution) -> read f32 there.
    int g0 = tid,         ra0 = g0 >> 3, ca0 = (g0 & 7) ^ (ra0 & 7);
    int g1 = 512 + tid,   ra1 = g1 >> 3, ca1 = (g1 & 7) ^ (ra1 & 7);
    int g2 = 1024 + tid,  ra2 = g2 >> 3, ca2 = (g2 & 7) ^ (ra2 & 7);
    int g3 = 1536 + tid,  ra3 = g3 >> 3, ca3 = (g3 & 7) ^ (ra3 & 7);
    int h0 = tid,         rb0 = h0 >> 3, cb0 = (h0 & 7) ^ (rb0 & 7);
    int h1 = 512 + tid,   rb1 = h1 >> 3, cb1 = (h1 & 7) ^ (rb1 & 7);

    const float* gx0 = X + (size_t)(bm * 256 + ra0) * K + ca0 * 8;
    const float* gx1 = X + (size_t)(bm * 256 + ra1) * K + ca1 * 8;
    const float* gx2 = X + (size_t)(bm * 256 + ra2) * K + ca2 * 8;
    const float* gx3 = X + (size_t)(bm * 256 + ra3) * K + ca3 * 8;
    const unsigned short* gB0 = B + (size_t)(bn * 128 + rb0) * K + cb0 * 8;
    const unsigned short* gB1 = B + (size_t)(bn * 128 + rb1) * K + cb1 * 8;

    const int dA0 = g0 * 16, dA1 = g1 * 16, dA2 = g2 * 16, dA3 = g3 * 16;
    const int dB0 = 32768 + h0 * 16, dB1 = 32768 + h1 * 16;

    // ---- fragment byte offsets within a stage (A at 0, B at 32768) ----
    const int aO0 = ((wm * 64 + t) * 64 + ((0 + q) ^ r8) * 8) * 2;
    const int aO1 = ((wm * 64 + t) * 64 + ((4 + q) ^ r8) * 8) * 2;
    const int bO0 = 32768 + ((wn * 64 + t) * 64 + ((0 + q) ^ r8) * 8) * 2;
    const int bO1 = 32768 + ((wn * 64 + t) * 64 + ((4 + q) ^ r8) * 8) * 2;

    floatx4 acc[4][4];
#pragma unroll
    for (int i = 0; i < 4; ++i)
#pragma unroll
        for (int j = 0; j < 4; ++j)
            acc[i][j] = (floatx4){0.f, 0.f, 0.f, 0.f};

#define ISSUE_A(d0,d1,d2,d3,d4,d5,d6,d7, kf)                        \
    {                                                               \
        d0 = *(const float4*)(gx0 + (kf));                          \
        d1 = *(const float4*)(gx0 + (kf) + 4);                      \
        d2 = *(const float4*)(gx1 + (kf));                          \
        d3 = *(const float4*)(gx1 + (kf) + 4);                      \
        d4 = *(const float4*)(gx2 + (kf));                          \
        d5 = *(const float4*)(gx2 + (kf) + 4);                      \
        d6 = *(const float4*)(gx3 + (kf));                          \
        d7 = *(const float4*)(gx3 + (kf) + 4);                      \
    }
#define STAGE_B(sp, ko)                                             \
    {                                                               \
        gload_lds16(gB0 + (ko), (sp) + dB0);                        \
        gload_lds16(gB1 + (ko), (sp) + dB1);                        \
    }
#define CVT_WRITE(sw, s0,s1,s2,s3,s4,s5,s6,s7)                      \
    {                                                               \
        uint4 v;                                                    \
        v.x = cvtpk(s0.x, s0.y); v.y = cvtpk(s0.z, s0.w);           \
        v.z = cvtpk(s1.x, s1.y); v.w = cvtpk(s1.z, s1.w);           \
        *(uint4*)((sw) + dA0) = v;                                  \
        v.x = cvtpk(s2.x, s2.y); v.y = cvtpk(s2.z, s2.w);           \
        v.z = cvtpk(s3.x, s3.y); v.w = cvtpk(s3.z, s3.w);           \
        *(uint4*)((sw) + dA1) = v;                                  \
        v.x = cvtpk(s4.x, s4.y); v.y = cvtpk(s4.z, s4.w);           \
        v.z = cvtpk(s5.x, s5.y); v.w = cvtpk(s5.z, s5.w);           \
        *(uint4*)((sw) + dA2) = v;                                  \
        v.x = cvtpk(s6.x, s6.y); v.y = cvtpk(s6.z, s6.w);           \
        v.z = cvtpk(s7.x, s7.y); v.w = cvtpk(s7.z, s7.w);           \
        *(uint4*)((sw) + dA3) = v;                                  \
    }
#define PHASE(sb, aO, bO)                                           \
    {                                                               \
        const char* ab = (const char*)(sb) + (aO);                  \
        const char* bb = (const char*)(sb) + (bO);                  \
        bf16x8 af0 = *(const bf16x8*)(ab + 0 * 2048);               \
        bf16x8 af1 = *(const bf16x8*)(ab + 1 * 2048);               \
        bf16x8 af2 = *(const bf16x8*)(ab + 2 * 2048);               \
        bf16x8 af3 = *(const bf16x8*)(ab + 3 * 2048);               \
        bf16x8 bf0 = *(const bf16x8*)(bb + 0 * 2048);               \
        bf16x8 bf1 = *(const bf16x8*)(bb + 1 * 2048);               \
        bf16x8 bf2 = *(const bf16x8*)(bb + 2 * 2048);               \
        bf16x8 bf3 = *(const bf16x8*)(bb + 3 * 2048);               \
        bf16x8 afv[4] = {af0, af1, af2, af3};                       \
        bf16x8 bfv[4] = {bf0, bf1, bf2, bf3};                       \
        __builtin_amdgcn_s_setprio(1);                              \
        _Pragma("unroll")                                           \
        for (int i = 0; i < 4; ++i)                                 \
            _Pragma("unroll")                                       \
            for (int j = 0; j < 4; ++j)                             \
                acc[i][j] = __builtin_amdgcn_mfma_f32_16x16x32_bf16(\
                    afv[i], bfv[j], acc[i][j], 0, 0, 0);            \
        __builtin_amdgcn_s_setprio(0);                              \
    }

    float4 pa0, pa1, pa2, pa3, pa4, pa5, pa6, pa7;   // A(kt+1) f32
    float4 na0, na1, na2, na3, na4, na5, na6, na7;   // A(kt+2) f32

    // ---- prologue ----
    // A(0)->na, B(0)->s0, A(1)->pa, B(1)->s1; cvt+write A(0)->s0;
    // vmcnt(10): B(0) retired, A(1)+B(1)=10 in flight.
    ISSUE_A(na0,na1,na2,na3,na4,na5,na6,na7, 0);
    STAGE_B(smem, 0);
    ISSUE_A(pa0,pa1,pa2,pa3,pa4,pa5,pa6,pa7, 64);
    STAGE_B(smem + STG, BK);
    CVT_WRITE(smem, na0,na1,na2,na3,na4,na5,na6,na7);
    WAIT_V10L0();
    BARRIER();

    // ---- main loop: 2x-unrolled ping-pong, kt = 0..13 ----
    int cur = 0;
    for (int it = 0; it < 7; ++it) {
        const int kt0 = 2 * it, kt1 = kt0 + 1;
        {   // even: compute kt0; write A(kt0+1)=pa late; load na=A(kt0+2)
            char* sb = smem + cur * STG;
            int w1 = cur + 1; if (w1 >= 3) w1 -= 3;
            int p2 = cur + 2; if (p2 >= 3) p2 -= 3;
            ISSUE_A(na0,na1,na2,na3,na4,na5,na6,na7, (kt0 + 2) * 64);
            STAGE_B(smem + p2 * STG, (kt0 + 2) * BK);
            PHASE(sb, aO0, bO0);
            PHASE(sb, aO1, bO1);
            CVT_WRITE(smem + w1 * STG, pa0,pa1,pa2,pa3,pa4,pa5,pa6,pa7);
            WAIT_V10L0();
            BARRIER();
            cur = w1;
        }
        {   // odd: compute kt1; write A(kt1+1)=na late; load pa=A(kt1+2)
            char* sb = smem + cur * STG;
            int w1 = cur + 1; if (w1 >= 3) w1 -= 3;
            int p2 = cur + 2; if (p2 >= 3) p2 -= 3;
            ISSUE_A(pa0,pa1,pa2,pa3,pa4,pa5,pa6,pa7, (kt1 + 2) * 64);
            STAGE_B(smem + p2 * STG, (kt1 + 2) * BK);
            PHASE(sb, aO0, bO0);
            PHASE(sb, aO1, bO1);
            CVT_WRITE(smem + w1 * STG, na0,na1,na2,na3,na4,na5,na6,na7);
            WAIT_V10L0();
            BARRIER();
            cur = w1;
        }
    }
    {   // kt = 14: compute; write A(15)=pa late; no new issues; drain
        char* sb = smem + cur * STG;
        int w1 = cur + 1; if (w1 >= 3) w1 -= 3;
        PHASE(sb, aO0, bO0);
        PHASE(sb, aO1, bO1);
        CVT_WRITE(smem + w1 * STG, pa0,pa1,pa2,pa3,pa4,pa5,pa6,pa7);
        WAIT_V0L0();
        BARRIER();
        cur = w1;
    }
    {   // kt = 15
        char* sb = smem + cur * STG;
        PHASE(sb, aO0, bO0);
        PHASE(sb, aO1, bO1);
    }
#undef PHASE
#undef CVT_WRITE
#undef STAGE_B
#undef ISSUE_A

    __syncthreads();   // full drain before LDS reuse as ebuf

    // ---- epilogue: dump 256x128 f32 via LDS (ES=132 pad), float4 out ----
    // D layout: col = t, row = q*4 + r  [m89/m91 verified]
#pragma unroll
    for (int tm = 0; tm < 4; ++tm)
#pragma unroll
        for (int tn = 0; tn < 4; ++tn)
#pragma unroll
            for (int r = 0; r < 4; ++r)
                ebuf[(wm * 64 + tm * 16 + q * 4 + r) * ES
                     + wn * 64 + tn * 16 + t] = acc[tm][tn][r];
    __syncthreads();
#pragma unroll
    for (int ps = 0; ps < 16; ++ps) {
        int row  = ps * 16 + (tid >> 5);
        int col4 = tid & 31;
        float4 v = *(const float4*)(ebuf + row * ES + col4 * 4);
        *(float4*)(C + (size_t)(bm * 256 + row) * OUTD + bn * 128 + col4 * 4) = v;
    }
}

extern "C" void kernel_launch(void* const* d_in, const int* in_sizes, int n_in,
                              void* d_out, int out_size, void* d_ws, size_t ws_size,
                              hipStream_t stream) {
    const float* x    = (const float*)d_in[0];
    const float* coef = (const float*)d_in[1];
    const float* w    = (const float*)d_in[2];
    float* out = (float*)d_out;

    unsigned short* weff = (unsigned short*)d_ws;   // 2 MB

    prep_kernel<<<2048, 256, 0, stream>>>(coef, w, weff);
    gemm_bt<<<dim3(BATCH / 256, OUTD / 128), 512, 0, stream>>>(x, weff, out);
}